// Round 5
// baseline (113.350 us; speedup 1.0000x reference)
//
#include <hip/hip_runtime.h>
#include <hip/hip_bf16.h>
#include <math.h>

// Problem constants
#define DD  512
#define EE  8
#define FFD 2048
#define TT  2048
#define HWH 1024

typedef __bf16 b16x8 __attribute__((ext_vector_type(8)));
typedef float  f32x4 __attribute__((ext_vector_type(4)));

__device__ __forceinline__ unsigned short f2bf(float f) {
    unsigned u = __builtin_bit_cast(unsigned, f);
    u = (u + 0x7FFFu + ((u >> 16) & 1u)) >> 16;   // RNE
    return (unsigned short)u;
}

// async global->LDS, 16B per lane; LDS dest is wave-uniform base + lane*16
__device__ __forceinline__ void gload16(const void* g, void* l) {
    __builtin_amdgcn_global_load_lds(
        (const __attribute__((address_space(1))) void*)g,
        (__attribute__((address_space(3))) void*)l, 16, 0, 0);
}

// ---------- prep: weight/x transpose-convert + router partial GEMV ---------
// z=0: W1[e] 512x2048 f32 -> W1t[e] 2048x512 bf16
// z=1: W2[e] 2048x512 f32 -> W2t[e] 512x2048 bf16
// z=2: x[b]  512x1024 f32 -> xb[b] 1024x512 bf16
// z=3: router partial GEMV (independent work, overlaps the transposes)
__global__ __launch_bounds__(256) void moe_prep(
    const float* __restrict__ W1, const float* __restrict__ W2,
    const float* __restrict__ x,
    unsigned short* __restrict__ W1t, unsigned short* __restrict__ W2t,
    unsigned short* __restrict__ xb,
    const float* __restrict__ Wg, const float* __restrict__ Wn,
    float* __restrict__ part)
{
    __shared__ float ld[64][65];
    int which = blockIdx.z, e = blockIdx.y;

    if (which == 3) {
        // ---- router partial: block (tt, dc) reduces a 64-d slice ----
        if (blockIdx.x >= 32) return;
        int u = threadIdx.x & 63;
        int q = threadIdx.x >> 6;
        int tt = blockIdx.x, dc = e;
        int t = tt * 64 + u;
        int b = t >> 10, hw = t & 1023;
        const float* xp = x + (size_t)b * DD * HWH + hw;
        int d0 = dc * 64 + q * 16;
        float accL[EE], accN[EE];
        #pragma unroll
        for (int k = 0; k < EE; ++k) { accL[k] = 0.f; accN[k] = 0.f; }
        #pragma unroll
        for (int i = 0; i < 16; ++i) {
            int d = d0 + i;
            float tv = xp[(size_t)d * HWH];
            #pragma unroll
            for (int k = 0; k < EE; ++k) {
                accL[k] = fmaf(tv, Wg[d * EE + k], accL[k]);
                accN[k] = fmaf(tv, Wn[d * EE + k], accN[k]);
            }
        }
        float (*s)[64][16] = (float (*)[64][16])&ld[0][0];   // 16KB reuse
        #pragma unroll
        for (int k = 0; k < EE; ++k) { s[q][u][k] = accL[k]; s[q][u][k + 8] = accN[k]; }
        __syncthreads();
        int idx = threadIdx.x * 4;
        int ot = idx >> 4, oc = idx & 15;
        float4 v;
        v.x = s[0][ot][oc+0] + s[1][ot][oc+0] + s[2][ot][oc+0] + s[3][ot][oc+0];
        v.y = s[0][ot][oc+1] + s[1][ot][oc+1] + s[2][ot][oc+1] + s[3][ot][oc+1];
        v.z = s[0][ot][oc+2] + s[1][ot][oc+2] + s[2][ot][oc+2] + s[3][ot][oc+2];
        v.w = s[0][ot][oc+3] + s[1][ot][oc+3] + s[2][ot][oc+3] + s[3][ot][oc+3];
        *(float4*)&part[((size_t)dc * TT + tt * 64 + ot) * 16 + oc] = v;
        return;
    }

    const float* in; unsigned short* out; int R, C;
    if (which == 0)      { R = DD;  C = FFD; in = W1 + (size_t)e*DD*FFD; out = W1t + (size_t)e*FFD*DD; }
    else if (which == 1) { R = FFD; C = DD;  in = W2 + (size_t)e*FFD*DD; out = W2t + (size_t)e*DD*FFD; }
    else { if (e >= 2) return; R = DD; C = HWH; in = x + (size_t)e*DD*HWH; out = xb + (size_t)e*HWH*DD; }
    int tilesC = C >> 6;
    if ((int)blockIdx.x >= (R >> 6) * tilesC) return;
    int tr = (blockIdx.x / tilesC) << 6, tc = (blockIdx.x % tilesC) << 6;
    int ty = threadIdx.x >> 4, tx = threadIdx.x & 15;
    #pragma unroll
    for (int i = 0; i < 4; ++i) {
        const float4 v = *(const float4*)&in[(size_t)(tr + ty + i*16)*C + tc + tx*4];
        ld[ty + i*16][tx*4+0] = v.x; ld[ty + i*16][tx*4+1] = v.y;
        ld[ty + i*16][tx*4+2] = v.z; ld[ty + i*16][tx*4+3] = v.w;
    }
    __syncthreads();
    #pragma unroll
    for (int i = 0; i < 4; ++i) {
        int c = ty + i*16;
        unsigned o0 = f2bf(ld[tx*4+0][c]) | ((unsigned)f2bf(ld[tx*4+1][c]) << 16);
        unsigned o1 = f2bf(ld[tx*4+2][c]) | ((unsigned)f2bf(ld[tx*4+3][c]) << 16);
        *(uint2*)&out[(size_t)(tc + c)*R + tr + tx*4] = make_uint2(o0, o1);
    }
}

// ---------------- Router stage B: reduce + noisy top-2 + gates -------------
__global__ __launch_bounds__(256) void moe_router_topk(
    const float* __restrict__ part,
    const float* __restrict__ bg, const float* __restrict__ bn,
    const float* __restrict__ neps,
    int* __restrict__ cnt, int* __restrict__ pair0, int* __restrict__ pair1,
    int* __restrict__ ltok, float* __restrict__ lgate)
{
    int t = blockIdx.x * 256 + threadIdx.x;
    float L[EE], N[EE];
    #pragma unroll
    for (int e = 0; e < EE; ++e) { L[e] = bg[e]; N[e] = bn[e]; }
    #pragma unroll
    for (int dc = 0; dc < 8; ++dc) {
        const float* p = &part[((size_t)dc * TT + t) * 16];
        float4 a0 = *(const float4*)&p[0];
        float4 a1 = *(const float4*)&p[4];
        float4 a2 = *(const float4*)&p[8];
        float4 a3 = *(const float4*)&p[12];
        L[0] += a0.x; L[1] += a0.y; L[2] += a0.z; L[3] += a0.w;
        L[4] += a1.x; L[5] += a1.y; L[6] += a1.z; L[7] += a1.w;
        N[0] += a2.x; N[1] += a2.y; N[2] += a2.z; N[3] += a2.w;
        N[4] += a3.x; N[5] += a3.y; N[6] += a3.z; N[7] += a3.w;
    }
    float noisy[EE];
    #pragma unroll
    for (int e = 0; e < EE; ++e) {
        float sp = fmaxf(N[e], 0.f) + log1pf(expf(-fabsf(N[e])));   // softplus
        noisy[e] = L[e] + neps[t * EE + e] * sp;
    }
    int e0 = 0; float v0 = noisy[0];
    #pragma unroll
    for (int e = 1; e < EE; ++e) if (noisy[e] > v0) { v0 = noisy[e]; e0 = e; }
    int e1 = (e0 == 0) ? 1 : 0; float v1 = noisy[e1];
    #pragma unroll
    for (int e = 0; e < EE; ++e)
        if (e != e0 && e != e1 && noisy[e] > v1) { v1 = noisy[e]; e1 = e; }
    float ex  = expf(v1 - v0);
    float inv = 1.f / (1.f + ex);
    float g0 = inv, g1 = ex * inv;
    int p0 = atomicAdd(&cnt[e0], 1);
    int p1 = atomicAdd(&cnt[e1], 1);
    ltok[e0 * TT + p0] = t; lgate[e0 * TT + p0] = g0;
    ltok[e1 * TT + p1] = t; lgate[e1 * TT + p1] = g1;
    pair0[t] = (e0 << 16) | p0;
    pair1[t] = (e1 << 16) | p1;
}

// ---------------- Prefix sum over 8 expert counts --------------------------
__global__ void moe_prefix(const int* __restrict__ cnt, int* __restrict__ seg)
{
    if (threadIdx.x == 0) {
        int s = 0;
        for (int e = 0; e < EE; ++e) { seg[e] = s; s += cnt[e]; }
        seg[EE] = s;
    }
}

// ---------------- GEMM1: H = relu(tok @ W1t^T + b1) ------------------------
// 64x128 tile, BK=32, dbuf LDS (24KB), gload_lds w/ source-side chunk XOR.
// Flat XCD-aware grid: id = p*256 + mt*8 + c ; (e,nt) = p*8+c ; mt-siblings
// (sharing the weight panel) are congruent mod 8 -> same XCD L2.
__global__ __launch_bounds__(256, 4) void moe_gemm1(
    const unsigned short* __restrict__ xb, const unsigned short* __restrict__ W1t,
    const float* __restrict__ b1, const int* __restrict__ cnt,
    const int* __restrict__ seg, const int* __restrict__ ltok,
    unsigned short* __restrict__ Hbuf)
{
    int id = blockIdx.x;
    int c8 = id & 7;
    int mt = (id >> 3) & 31;
    int p  = id >> 8;
    int combo = p * 8 + c8;          // 0..127
    int e  = combo >> 4;
    int nt = combo & 15;
    int ce = cnt[e];
    if (mt * 64 >= ce) return;
    int s0 = seg[e];
    const unsigned short* Be = W1t + (size_t)e * FFD * DD;   // [FF][D] bf16
    __shared__ unsigned short As[2][64 * 32];
    __shared__ unsigned short Bs[2][128 * 32];
    int tid = threadIdx.x, lane = tid & 63, wv = tid >> 6;

    // staging: thread -> (row = tid>>2, chunk = tid&3), source chunk XORed
    int rA = tid >> 2, cc = tid & 3;
    int ri = mt * 64 + rA;
    int tokA = ltok[e * TT + (ri < ce ? ri : 0)];
    size_t aoff = (size_t)tokA * DD + ((cc ^ ((rA >> 1) & 3)) << 3);
    int rB0 = rA, rB1 = rA + 64;
    size_t boff0 = (size_t)(nt*128 + rB0) * DD + ((cc ^ ((rB0 >> 1) & 3)) << 3);
    size_t boff1 = (size_t)(nt*128 + rB1) * DD + ((cc ^ ((rB1 >> 1) & 3)) << 3);
    int wb = wv * 512;               // wave-uniform LDS elem base

    int frow = lane & 15, chR = lane >> 4;
    int am = (wv >> 1) * 32, bnn = (wv & 1) * 64;

    f32x4 acc[2][4];
    f32x4 zero = {0.f, 0.f, 0.f, 0.f};
    #pragma unroll
    for (int m = 0; m < 2; ++m)
        #pragma unroll
        for (int n = 0; n < 4; ++n) acc[m][n] = zero;

    // prologue
    gload16(&xb[aoff], &As[0][wb]);
    gload16(&Be[boff0], &Bs[0][wb]);
    gload16(&Be[boff1], &Bs[0][2048 + wb]);
    __syncthreads();

    int cur = 0;
    for (int t = 0; t < 16; ++t) {
        if (t < 15) {
            int kk = (t + 1) * 32;
            gload16(&xb[aoff + kk], &As[cur^1][wb]);
            gload16(&Be[boff0 + kk], &Bs[cur^1][wb]);
            gload16(&Be[boff1 + kk], &Bs[cur^1][2048 + wb]);
        }
        b16x8 af[2], bf[4];
        #pragma unroll
        for (int m = 0; m < 2; ++m) {
            int ra = am + m*16 + frow;
            af[m] = *(const b16x8*)&As[cur][ra*32 + ((chR ^ ((ra>>1)&3)) << 3)];
        }
        #pragma unroll
        for (int n = 0; n < 4; ++n) {
            int rb = bnn + n*16 + frow;
            bf[n] = *(const b16x8*)&Bs[cur][rb*32 + ((chR ^ ((rb>>1)&3)) << 3)];
        }
        #pragma unroll
        for (int m = 0; m < 2; ++m)
            #pragma unroll
            for (int n = 0; n < 4; ++n)
                acc[m][n] = __builtin_amdgcn_mfma_f32_16x16x32_bf16(af[m], bf[n], acc[m][n], 0, 0, 0);
        __syncthreads();
        cur ^= 1;
    }

    int crow = (lane >> 4) * 4;
    #pragma unroll
    for (int m = 0; m < 2; ++m) {
        #pragma unroll
        for (int i = 0; i < 4; ++i) {
            int r = mt*64 + am + m*16 + crow + i;
            if (r < ce) {
                size_t hrow = (size_t)(s0 + r) * FFD;
                #pragma unroll
                for (int n = 0; n < 4; ++n) {
                    int col = nt*128 + bnn + n*16 + frow;
                    float v = acc[m][n][i] + b1[e * FFD + col];
                    Hbuf[hrow + col] = f2bf(fmaxf(v, 0.f));
                }
            }
        }
    }
}

// ---------------- GEMM2: P4[s] = H @ W2t^T  (split-K x4) -------------------
// 64x128 tile, BK=32; z = combo&15 -> split = z>>2, nt = z&3.
__global__ __launch_bounds__(256, 4) void moe_gemm2(
    const unsigned short* __restrict__ Hbuf, const unsigned short* __restrict__ W2t,
    const int* __restrict__ cnt, const int* __restrict__ seg,
    float* __restrict__ P4)
{
    int id = blockIdx.x;
    int c8 = id & 7;
    int mt = (id >> 3) & 31;
    int p  = id >> 8;
    int combo = p * 8 + c8;
    int e  = combo >> 4;
    int z  = combo & 15;
    int split = z >> 2, nt = z & 3;
    int ce = cnt[e];
    if (mt * 64 >= ce) return;
    int s0 = seg[e];
    int kbase = split * 512;
    const unsigned short* Be = W2t + (size_t)e * DD * FFD;   // [D][FF] bf16
    __shared__ unsigned short As[2][64 * 32];
    __shared__ unsigned short Bs[2][128 * 32];
    int tid = threadIdx.x, lane = tid & 63, wv = tid >> 6;

    int rA = tid >> 2, cc = tid & 3;
    int g = s0 + mt*64 + rA; if (g > 4095) g = 4095;
    size_t aoff = (size_t)g * FFD + kbase + ((cc ^ ((rA >> 1) & 3)) << 3);
    int rB0 = rA, rB1 = rA + 64;
    size_t boff0 = (size_t)(nt*128 + rB0) * FFD + kbase + ((cc ^ ((rB0 >> 1) & 3)) << 3);
    size_t boff1 = (size_t)(nt*128 + rB1) * FFD + kbase + ((cc ^ ((rB1 >> 1) & 3)) << 3);
    int wb = wv * 512;

    int frow = lane & 15, chR = lane >> 4;
    int am = (wv >> 1) * 32, bnn = (wv & 1) * 64;

    f32x4 acc[2][4];
    f32x4 zero = {0.f, 0.f, 0.f, 0.f};
    #pragma unroll
    for (int m = 0; m < 2; ++m)
        #pragma unroll
        for (int n = 0; n < 4; ++n) acc[m][n] = zero;

    gload16(&Hbuf[aoff], &As[0][wb]);
    gload16(&Be[boff0], &Bs[0][wb]);
    gload16(&Be[boff1], &Bs[0][2048 + wb]);
    __syncthreads();

    int cur = 0;
    for (int t = 0; t < 16; ++t) {
        if (t < 15) {
            int kk = (t + 1) * 32;
            gload16(&Hbuf[aoff + kk], &As[cur^1][wb]);
            gload16(&Be[boff0 + kk], &Bs[cur^1][wb]);
            gload16(&Be[boff1 + kk], &Bs[cur^1][2048 + wb]);
        }
        b16x8 af[2], bf[4];
        #pragma unroll
        for (int m = 0; m < 2; ++m) {
            int ra = am + m*16 + frow;
            af[m] = *(const b16x8*)&As[cur][ra*32 + ((chR ^ ((ra>>1)&3)) << 3)];
        }
        #pragma unroll
        for (int n = 0; n < 4; ++n) {
            int rb = bnn + n*16 + frow;
            bf[n] = *(const b16x8*)&Bs[cur][rb*32 + ((chR ^ ((rb>>1)&3)) << 3)];
        }
        #pragma unroll
        for (int m = 0; m < 2; ++m)
            #pragma unroll
            for (int n = 0; n < 4; ++n)
                acc[m][n] = __builtin_amdgcn_mfma_f32_16x16x32_bf16(af[m], bf[n], acc[m][n], 0, 0, 0);
        __syncthreads();
        cur ^= 1;
    }

    int crow = (lane >> 4) * 4;
    float* Pw = P4 + (size_t)split * 4096 * DD;
    #pragma unroll
    for (int m = 0; m < 2; ++m) {
        #pragma unroll
        for (int i = 0; i < 4; ++i) {
            int r = mt*64 + am + m*16 + crow + i;
            if (r < ce) {
                size_t prow = (size_t)(s0 + r) * DD;
                #pragma unroll
                for (int n = 0; n < 4; ++n) {
                    int col = nt*128 + bnn + n*16 + frow;
                    Pw[prow + col] = acc[m][n][i];
                }
            }
        }
    }
}

// ------ Combine: out[t,d] = sum_pairs gate*(sum_splits P4 + b2[e])  --------
__global__ __launch_bounds__(256) void moe_combine(
    const int* __restrict__ pair0, const int* __restrict__ pair1,
    const int* __restrict__ seg, const float* __restrict__ lgate,
    const float* __restrict__ b2, const float* __restrict__ P4,
    float* __restrict__ out)
{
    __shared__ float tile[32][68];
    int tid = threadIdx.x;
    int ti = blockIdx.x, dc = blockIdx.y;
    int ty = tid >> 3, tx = tid & 7;
    int t = ti * 32 + ty;
    int a0 = pair0[t], a1 = pair1[t];
    int e0 = a0 >> 16, sl0 = a0 & 0xFFFF;
    int e1 = a1 >> 16, sl1 = a1 & 0xFFFF;
    int p0 = seg[e0] + sl0, p1 = seg[e1] + sl1;
    float g0 = lgate[e0 * TT + sl0], g1 = lgate[e1 * TT + sl1];
    int d0 = dc * 64 + tx * 8;
    f32x4 s0v[2] = {{0,0,0,0},{0,0,0,0}}, s1v[2] = {{0,0,0,0},{0,0,0,0}};
    #pragma unroll
    for (int s = 0; s < 4; ++s) {
        const f32x4* r0p = (const f32x4*)(P4 + ((size_t)s * 4096 + p0) * DD + d0);
        const f32x4* r1p = (const f32x4*)(P4 + ((size_t)s * 4096 + p1) * DD + d0);
        s0v[0] += r0p[0]; s0v[1] += r0p[1];
        s1v[0] += r1p[0]; s1v[1] += r1p[1];
    }
    const f32x4* b0p = (const f32x4*)(b2 + e0 * DD + d0);
    const f32x4* b1p = (const f32x4*)(b2 + e1 * DD + d0);
    #pragma unroll
    for (int q = 0; q < 2; ++q) {
        f32x4 v = g0 * (s0v[q] + b0p[q]) + g1 * (s1v[q] + b1p[q]);
        *(f32x4*)&tile[ty][tx*8 + q*4] = v;
    }
    __syncthreads();
    int dy = tid >> 2, hx = tid & 3;
    int b = (ti * 32) >> 10, hw0 = (ti * 32) & 1023;
    size_t obase = ((size_t)(b * DD + dc * 64 + dy)) * HWH + hw0;
    #pragma unroll
    for (int q = 0; q < 2; ++q) {
        int j = hx * 8 + q * 4;
        float4 w;
        w.x = tile[j + 0][dy];
        w.y = tile[j + 1][dy];
        w.z = tile[j + 2][dy];
        w.w = tile[j + 3][dy];
        *(float4*)&out[obase + j] = w;
    }
}

// ---------------- Launch ---------------------------------------------------
extern "C" void kernel_launch(void* const* d_in, const int* in_sizes, int n_in,
                              void* d_out, int out_size, void* d_ws, size_t ws_size,
                              hipStream_t stream)
{
    const float* x    = (const float*)d_in[0];
    const float* Wg   = (const float*)d_in[1];
    const float* bg   = (const float*)d_in[2];
    const float* Wn   = (const float*)d_in[3];
    const float* bn   = (const float*)d_in[4];
    const float* W1   = (const float*)d_in[5];
    const float* b1   = (const float*)d_in[6];
    const float* W2   = (const float*)d_in[7];
    const float* b2   = (const float*)d_in[8];
    const float* neps = (const float*)d_in[9];

    char* ws = (char*)d_ws;
    int*   cnt   = (int*)(ws + 0);                       // 32 B
    int*   seg   = (int*)(ws + 256);                     // 36 B
    int*   pair0 = (int*)(ws + 512);                     // 8 KB
    int*   pair1 = (int*)(ws + 8704);                    // 8 KB
    int*   ltok  = (int*)(ws + 32768);                   // 64 KB
    float* lgate = (float*)(ws + 98304);                 // 64 KB
    float* part  = (float*)(ws + 163840);                // 1 MB [8][2048][16] f32
    unsigned short* xb   = (unsigned short*)(ws + 1212416);   // 2 MB  [2048][512] bf16
    unsigned short* Hbuf = (unsigned short*)(ws + 3309568);   // 16 MB [4096][2048] bf16
    unsigned short* W1t  = (unsigned short*)(ws + 20086784);  // 16 MB [E][2048][512] bf16
    unsigned short* W2t  = (unsigned short*)(ws + 36864000);  // 16 MB [E][512][2048] bf16
    float*          P4   = (float*)(ws + 53641216);           // 32 MB [4][4096][512] f32

    hipMemsetAsync(cnt, 0, 32, stream);
    moe_prep<<<dim3(256, 8, 4), 256, 0, stream>>>(W1, W2, x, W1t, W2t, xb, Wg, Wn, part);
    moe_router_topk<<<TT / 256, 256, 0, stream>>>(part, bg, bn, neps,
                                                  cnt, pair0, pair1, ltok, lgate);
    moe_prefix<<<1, 64, 0, stream>>>(cnt, seg);
    moe_gemm1<<<4096, 256, 0, stream>>>(xb, W1t, b1, cnt, seg, ltok, Hbuf);
    moe_gemm2<<<4096, 256, 0, stream>>>(Hbuf, W2t, cnt, seg, P4);
    moe_combine<<<dim3(TT / 32, 8), 256, 0, stream>>>(pair0, pair1, seg, lgate, b2, P4, (float*)d_out);
}

// Round 6
// 102.017 us; speedup vs baseline: 1.1111x; 1.1111x over previous
//
#include <hip/hip_runtime.h>
#include <hip/hip_bf16.h>
#include <math.h>

// Problem constants
#define DD  512
#define EE  8
#define FFD 2048
#define TT  2048
#define HWH 1024

typedef __bf16 b16x8 __attribute__((ext_vector_type(8)));
typedef float  f32x4 __attribute__((ext_vector_type(4)));

__device__ __forceinline__ unsigned short f2bf(float f) {
    unsigned u = __builtin_bit_cast(unsigned, f);
    u = (u + 0x7FFFu + ((u >> 16) & 1u)) >> 16;   // RNE
    return (unsigned short)u;
}

// async global->LDS, 16B per lane; LDS dest is wave-uniform base + lane*16
__device__ __forceinline__ void gload16(const void* g, void* l) {
    __builtin_amdgcn_global_load_lds(
        (const __attribute__((address_space(1))) void*)g,
        (__attribute__((address_space(3))) void*)l, 16, 0, 0);
}

// prefix over cnt without runtime-indexed array (rule #20)
__device__ __forceinline__ int seg_pred(const int* __restrict__ cnt, int e) {
    int s = 0;
    #pragma unroll
    for (int i = 0; i < EE; ++i) s += (i < e) ? cnt[i] : 0;
    return s;
}

// ---------- prep: weight/x transpose-convert + router partial GEMV ---------
// z=0: W1[e] 512x2048 f32 -> W1t[e] 2048x512 bf16
// z=1: W2[e] 2048x512 f32 -> W2t[e] 512x2048 bf16
// z=2: x[b]  512x1024 f32 -> xb[b] 1024x512 bf16
// z=3: router partial GEMV (independent work, overlaps the transposes)
__global__ __launch_bounds__(256) void moe_prep(
    const float* __restrict__ W1, const float* __restrict__ W2,
    const float* __restrict__ x,
    unsigned short* __restrict__ W1t, unsigned short* __restrict__ W2t,
    unsigned short* __restrict__ xb,
    const float* __restrict__ Wg, const float* __restrict__ Wn,
    float* __restrict__ part)
{
    __shared__ float ld[64][65];
    int which = blockIdx.z, e = blockIdx.y;

    if (which == 3) {
        if (blockIdx.x >= 32) return;
        int u = threadIdx.x & 63;
        int q = threadIdx.x >> 6;
        int tt = blockIdx.x, dc = e;
        int t = tt * 64 + u;
        int b = t >> 10, hw = t & 1023;
        const float* xp = x + (size_t)b * DD * HWH + hw;
        int d0 = dc * 64 + q * 16;
        float accL[EE], accN[EE];
        #pragma unroll
        for (int k = 0; k < EE; ++k) { accL[k] = 0.f; accN[k] = 0.f; }
        #pragma unroll
        for (int i = 0; i < 16; ++i) {
            int d = d0 + i;
            float tv = xp[(size_t)d * HWH];
            #pragma unroll
            for (int k = 0; k < EE; ++k) {
                accL[k] = fmaf(tv, Wg[d * EE + k], accL[k]);
                accN[k] = fmaf(tv, Wn[d * EE + k], accN[k]);
            }
        }
        float (*s)[64][16] = (float (*)[64][16])&ld[0][0];
        #pragma unroll
        for (int k = 0; k < EE; ++k) { s[q][u][k] = accL[k]; s[q][u][k + 8] = accN[k]; }
        __syncthreads();
        int idx = threadIdx.x * 4;
        int ot = idx >> 4, oc = idx & 15;
        float4 v;
        v.x = s[0][ot][oc+0] + s[1][ot][oc+0] + s[2][ot][oc+0] + s[3][ot][oc+0];
        v.y = s[0][ot][oc+1] + s[1][ot][oc+1] + s[2][ot][oc+1] + s[3][ot][oc+1];
        v.z = s[0][ot][oc+2] + s[1][ot][oc+2] + s[2][ot][oc+2] + s[3][ot][oc+2];
        v.w = s[0][ot][oc+3] + s[1][ot][oc+3] + s[2][ot][oc+3] + s[3][ot][oc+3];
        *(float4*)&part[((size_t)dc * TT + tt * 64 + ot) * 16 + oc] = v;
        return;
    }

    const float* in; unsigned short* out; int R, C;
    if (which == 0)      { R = DD;  C = FFD; in = W1 + (size_t)e*DD*FFD; out = W1t + (size_t)e*FFD*DD; }
    else if (which == 1) { R = FFD; C = DD;  in = W2 + (size_t)e*FFD*DD; out = W2t + (size_t)e*DD*FFD; }
    else { if (e >= 2) return; R = DD; C = HWH; in = x + (size_t)e*DD*HWH; out = xb + (size_t)e*HWH*DD; }
    int tilesC = C >> 6;
    if ((int)blockIdx.x >= (R >> 6) * tilesC) return;
    int tr = (blockIdx.x / tilesC) << 6, tc = (blockIdx.x % tilesC) << 6;
    int ty = threadIdx.x >> 4, tx = threadIdx.x & 15;
    #pragma unroll
    for (int i = 0; i < 4; ++i) {
        const float4 v = *(const float4*)&in[(size_t)(tr + ty + i*16)*C + tc + tx*4];
        ld[ty + i*16][tx*4+0] = v.x; ld[ty + i*16][tx*4+1] = v.y;
        ld[ty + i*16][tx*4+2] = v.z; ld[ty + i*16][tx*4+3] = v.w;
    }
    __syncthreads();
    #pragma unroll
    for (int i = 0; i < 4; ++i) {
        int c = ty + i*16;
        unsigned o0 = f2bf(ld[tx*4+0][c]) | ((unsigned)f2bf(ld[tx*4+1][c]) << 16);
        unsigned o1 = f2bf(ld[tx*4+2][c]) | ((unsigned)f2bf(ld[tx*4+3][c]) << 16);
        *(uint2*)&out[(size_t)(tc + c)*R + tr + tx*4] = make_uint2(o0, o1);
    }
}

// ---------------- Router stage B: reduce + noisy top-2 + gates -------------
__global__ __launch_bounds__(256) void moe_router_topk(
    const float* __restrict__ part,
    const float* __restrict__ bg, const float* __restrict__ bn,
    const float* __restrict__ neps,
    int* __restrict__ cnt, int* __restrict__ pair0, int* __restrict__ pair1,
    int* __restrict__ ltok, float* __restrict__ lgate)
{
    int t = blockIdx.x * 256 + threadIdx.x;
    float L[EE], N[EE];
    #pragma unroll
    for (int e = 0; e < EE; ++e) { L[e] = bg[e]; N[e] = bn[e]; }
    #pragma unroll
    for (int dc = 0; dc < 8; ++dc) {
        const float* p = &part[((size_t)dc * TT + t) * 16];
        float4 a0 = *(const float4*)&p[0];
        float4 a1 = *(const float4*)&p[4];
        float4 a2 = *(const float4*)&p[8];
        float4 a3 = *(const float4*)&p[12];
        L[0] += a0.x; L[1] += a0.y; L[2] += a0.z; L[3] += a0.w;
        L[4] += a1.x; L[5] += a1.y; L[6] += a1.z; L[7] += a1.w;
        N[0] += a2.x; N[1] += a2.y; N[2] += a2.z; N[3] += a2.w;
        N[4] += a3.x; N[5] += a3.y; N[6] += a3.z; N[7] += a3.w;
    }
    float noisy[EE];
    #pragma unroll
    for (int e = 0; e < EE; ++e) {
        float sp = fmaxf(N[e], 0.f) + log1pf(expf(-fabsf(N[e])));   // softplus
        noisy[e] = L[e] + neps[t * EE + e] * sp;
    }
    int e0 = 0; float v0 = noisy[0];
    #pragma unroll
    for (int e = 1; e < EE; ++e) if (noisy[e] > v0) { v0 = noisy[e]; e0 = e; }
    int e1 = (e0 == 0) ? 1 : 0; float v1 = noisy[e1];
    #pragma unroll
    for (int e = 0; e < EE; ++e)
        if (e != e0 && e != e1 && noisy[e] > v1) { v1 = noisy[e]; e1 = e; }
    float ex  = expf(v1 - v0);
    float inv = 1.f / (1.f + ex);
    float g0 = inv, g1 = ex * inv;
    int p0 = atomicAdd(&cnt[e0], 1);
    int p1 = atomicAdd(&cnt[e1], 1);
    ltok[e0 * TT + p0] = t; lgate[e0 * TT + p0] = g0;
    ltok[e1 * TT + p1] = t; lgate[e1 * TT + p1] = g1;
    pair0[t] = (e0 << 16) | p0;
    pair1[t] = (e1 << 16) | p1;
}

// ---------------- GEMM1: H = relu(tok @ W1t^T + b1) ------------------------
// 64x128 tile, BK=64, dbuf LDS, counted-vmcnt never-drain pipeline (T3/T4).
__global__ __launch_bounds__(256, 3) void moe_gemm1(
    const unsigned short* __restrict__ xb, const unsigned short* __restrict__ W1t,
    const float* __restrict__ b1, const int* __restrict__ cnt,
    const int* __restrict__ ltok, unsigned short* __restrict__ Hbuf)
{
    int e = blockIdx.x, mt = blockIdx.y, nt = blockIdx.z;
    int ce = cnt[e];
    if (mt * 64 >= ce) return;
    int s0 = seg_pred(cnt, e);
    const unsigned short* Be = W1t + (size_t)e * FFD * DD;   // [FF][D] bf16
    __shared__ unsigned short As[2][64 * 64];
    __shared__ unsigned short Bs[2][128 * 64];
    int tid = threadIdx.x, lane = tid & 63, wv = tid >> 6;

    int srow = lane >> 3, schunk = lane & 7;
    int srcoff = ((schunk ^ srow) << 3);       // swizzled source chunk (elems)

    size_t aoff[2]; int ards[2];
    #pragma unroll
    for (int c = 0; c < 2; ++c) {
        int r0 = (c*4 + wv)*8;
        int ri = mt*64 + r0 + srow;
        int tok = ltok[e * TT + (ri < ce ? ri : 0)];
        aoff[c] = (size_t)tok * DD + srcoff;
        ards[c] = r0 * 64;                     // wave-uniform LDS base (elems)
    }
    size_t boff[4]; int brds[4];
    #pragma unroll
    for (int c = 0; c < 4; ++c) {
        int r0 = (c*4 + wv)*8;
        boff[c] = (size_t)(nt*128 + r0 + srow) * DD + srcoff;
        brds[c] = r0 * 64;
    }

    int frow = lane & 15, fk = (lane >> 4) * 8;
    int am = (wv >> 1) * 32, bnn = (wv & 1) * 64;
    int rx = (frow & 7) << 3;

    f32x4 acc[2][4];
    f32x4 zero = {0.f, 0.f, 0.f, 0.f};
    #pragma unroll
    for (int m = 0; m < 2; ++m)
        #pragma unroll
        for (int n = 0; n < 4; ++n) acc[m][n] = zero;

    // prologue: stage tiles 0 and 1 (6 wave-loads each; 12 in flight)
    #pragma unroll
    for (int c = 0; c < 2; ++c) gload16(&xb[aoff[c]], &As[0][ards[c]]);
    #pragma unroll
    for (int c = 0; c < 4; ++c) gload16(&Be[boff[c]], &Bs[0][brds[c]]);
    #pragma unroll
    for (int c = 0; c < 2; ++c) gload16(&xb[aoff[c] + 64], &As[1][ards[c]]);
    #pragma unroll
    for (int c = 0; c < 4; ++c) gload16(&Be[boff[c] + 64], &Bs[1][brds[c]]);

    #pragma unroll
    for (int t = 0; t < 8; ++t) {
        // wait only for the OLDEST staged tile; keep the next one in flight
        if (t < 6) { asm volatile("s_waitcnt vmcnt(6)" ::: "memory"); }
        else       { asm volatile("s_waitcnt vmcnt(0)" ::: "memory"); }
        __builtin_amdgcn_s_barrier();
        __builtin_amdgcn_sched_barrier(0);
        const int cur = t & 1;
        #pragma unroll
        for (int k2 = 0; k2 < 64; k2 += 32) {
            b16x8 af[2], bf[4];
            #pragma unroll
            for (int m = 0; m < 2; ++m)
                af[m] = *(const b16x8*)&As[cur][(am + m*16 + frow)*64 + ((k2 + fk) ^ rx)];
            #pragma unroll
            for (int n = 0; n < 4; ++n)
                bf[n] = *(const b16x8*)&Bs[cur][(bnn + n*16 + frow)*64 + ((k2 + fk) ^ rx)];
            #pragma unroll
            for (int m = 0; m < 2; ++m)
                #pragma unroll
                for (int n = 0; n < 4; ++n)
                    acc[m][n] = __builtin_amdgcn_mfma_f32_16x16x32_bf16(af[m], bf[n], acc[m][n], 0, 0, 0);
        }
        __builtin_amdgcn_s_barrier();          // all waves done reading buf[cur]
        if (t < 6) {
            int kk = (t + 2) * 64;
            #pragma unroll
            for (int c = 0; c < 2; ++c) gload16(&xb[aoff[c] + kk], &As[cur][ards[c]]);
            #pragma unroll
            for (int c = 0; c < 4; ++c) gload16(&Be[boff[c] + kk], &Bs[cur][brds[c]]);
        }
    }

    int crow = (lane >> 4) * 4;
    #pragma unroll
    for (int m = 0; m < 2; ++m) {
        #pragma unroll
        for (int i = 0; i < 4; ++i) {
            int r = mt*64 + am + m*16 + crow + i;
            if (r < ce) {
                size_t hrow = (size_t)(s0 + r) * FFD;
                #pragma unroll
                for (int n = 0; n < 4; ++n) {
                    int col = nt*128 + bnn + n*16 + frow;
                    float v = acc[m][n][i] + b1[e * FFD + col];
                    Hbuf[hrow + col] = f2bf(fmaxf(v, 0.f));
                }
            }
        }
    }
}

// ---------------- GEMM2: P4[s] = H @ W2t^T  (split-K x4) -------------------
// 64x128 tile, BK=64, same counted-vmcnt pipeline; z: split = z>>2, nt = z&3.
__global__ __launch_bounds__(256, 3) void moe_gemm2(
    const unsigned short* __restrict__ Hbuf, const unsigned short* __restrict__ W2t,
    const int* __restrict__ cnt, float* __restrict__ P4)
{
    int e = blockIdx.x, mt = blockIdx.y;
    int split = blockIdx.z >> 2, nt = blockIdx.z & 3;
    int ce = cnt[e];
    if (mt * 64 >= ce) return;
    int s0 = seg_pred(cnt, e);
    int kbase = split * 512;
    const unsigned short* Be = W2t + (size_t)e * DD * FFD;   // [D][FF] bf16
    __shared__ unsigned short As[2][64 * 64];
    __shared__ unsigned short Bs[2][128 * 64];
    int tid = threadIdx.x, lane = tid & 63, wv = tid >> 6;

    int srow = lane >> 3, schunk = lane & 7;
    int srcoff = ((schunk ^ srow) << 3);

    size_t aoff[2]; int ards[2];
    #pragma unroll
    for (int c = 0; c < 2; ++c) {
        int r0 = (c*4 + wv)*8;
        int g = s0 + mt*64 + r0 + srow; if (g > 4095) g = 4095;
        aoff[c] = (size_t)g * FFD + kbase + srcoff;
        ards[c] = r0 * 64;
    }
    size_t boff[4]; int brds[4];
    #pragma unroll
    for (int c = 0; c < 4; ++c) {
        int r0 = (c*4 + wv)*8;
        boff[c] = (size_t)(nt*128 + r0 + srow) * FFD + kbase + srcoff;
        brds[c] = r0 * 64;
    }

    int frow = lane & 15, fk = (lane >> 4) * 8;
    int am = (wv >> 1) * 32, bnn = (wv & 1) * 64;
    int rx = (frow & 7) << 3;

    f32x4 acc[2][4];
    f32x4 zero = {0.f, 0.f, 0.f, 0.f};
    #pragma unroll
    for (int m = 0; m < 2; ++m)
        #pragma unroll
        for (int n = 0; n < 4; ++n) acc[m][n] = zero;

    #pragma unroll
    for (int c = 0; c < 2; ++c) gload16(&Hbuf[aoff[c]], &As[0][ards[c]]);
    #pragma unroll
    for (int c = 0; c < 4; ++c) gload16(&Be[boff[c]], &Bs[0][brds[c]]);
    #pragma unroll
    for (int c = 0; c < 2; ++c) gload16(&Hbuf[aoff[c] + 64], &As[1][ards[c]]);
    #pragma unroll
    for (int c = 0; c < 4; ++c) gload16(&Be[boff[c] + 64], &Bs[1][brds[c]]);

    #pragma unroll
    for (int t = 0; t < 8; ++t) {
        if (t < 6) { asm volatile("s_waitcnt vmcnt(6)" ::: "memory"); }
        else       { asm volatile("s_waitcnt vmcnt(0)" ::: "memory"); }
        __builtin_amdgcn_s_barrier();
        __builtin_amdgcn_sched_barrier(0);
        const int cur = t & 1;
        #pragma unroll
        for (int k2 = 0; k2 < 64; k2 += 32) {
            b16x8 af[2], bf[4];
            #pragma unroll
            for (int m = 0; m < 2; ++m)
                af[m] = *(const b16x8*)&As[cur][(am + m*16 + frow)*64 + ((k2 + fk) ^ rx)];
            #pragma unroll
            for (int n = 0; n < 4; ++n)
                bf[n] = *(const b16x8*)&Bs[cur][(bnn + n*16 + frow)*64 + ((k2 + fk) ^ rx)];
            #pragma unroll
            for (int m = 0; m < 2; ++m)
                #pragma unroll
                for (int n = 0; n < 4; ++n)
                    acc[m][n] = __builtin_amdgcn_mfma_f32_16x16x32_bf16(af[m], bf[n], acc[m][n], 0, 0, 0);
        }
        __builtin_amdgcn_s_barrier();
        if (t < 6) {
            int kk = (t + 2) * 64;
            #pragma unroll
            for (int c = 0; c < 2; ++c) gload16(&Hbuf[aoff[c] + kk], &As[cur][ards[c]]);
            #pragma unroll
            for (int c = 0; c < 4; ++c) gload16(&Be[boff[c] + kk], &Bs[cur][brds[c]]);
        }
    }

    int crow = (lane >> 4) * 4;
    float* Pw = P4 + (size_t)split * 4096 * DD;
    #pragma unroll
    for (int m = 0; m < 2; ++m) {
        #pragma unroll
        for (int i = 0; i < 4; ++i) {
            int r = mt*64 + am + m*16 + crow + i;
            if (r < ce) {
                size_t prow = (size_t)(s0 + r) * DD;
                #pragma unroll
                for (int n = 0; n < 4; ++n) {
                    int col = nt*128 + bnn + n*16 + frow;
                    Pw[prow + col] = acc[m][n][i];
                }
            }
        }
    }
}

// ------ Combine: out[t,d] = sum_pairs gate*(sum_splits P4 + b2[e])  --------
__global__ __launch_bounds__(256) void moe_combine(
    const int* __restrict__ pair0, const int* __restrict__ pair1,
    const int* __restrict__ cnt, const float* __restrict__ lgate,
    const float* __restrict__ b2, const float* __restrict__ P4,
    float* __restrict__ out)
{
    __shared__ float tile[32][68];
    int tid = threadIdx.x;
    int ti = blockIdx.x, dc = blockIdx.y;
    int ty = tid >> 3, tx = tid & 7;
    int t = ti * 32 + ty;
    int a0 = pair0[t], a1 = pair1[t];
    int e0 = a0 >> 16, sl0 = a0 & 0xFFFF;
    int e1 = a1 >> 16, sl1 = a1 & 0xFFFF;
    int p0 = seg_pred(cnt, e0) + sl0, p1 = seg_pred(cnt, e1) + sl1;
    float g0 = lgate[e0 * TT + sl0], g1 = lgate[e1 * TT + sl1];
    int d0 = dc * 64 + tx * 8;
    f32x4 s0v[2] = {{0,0,0,0},{0,0,0,0}}, s1v[2] = {{0,0,0,0},{0,0,0,0}};
    #pragma unroll
    for (int s = 0; s < 4; ++s) {
        const f32x4* r0p = (const f32x4*)(P4 + ((size_t)s * 4096 + p0) * DD + d0);
        const f32x4* r1p = (const f32x4*)(P4 + ((size_t)s * 4096 + p1) * DD + d0);
        s0v[0] += r0p[0]; s0v[1] += r0p[1];
        s1v[0] += r1p[0]; s1v[1] += r1p[1];
    }
    const f32x4* b0p = (const f32x4*)(b2 + e0 * DD + d0);
    const f32x4* b1p = (const f32x4*)(b2 + e1 * DD + d0);
    #pragma unroll
    for (int q = 0; q < 2; ++q) {
        f32x4 v = g0 * (s0v[q] + b0p[q]) + g1 * (s1v[q] + b1p[q]);
        *(f32x4*)&tile[ty][tx*8 + q*4] = v;
    }
    __syncthreads();
    int dy = tid >> 2, hx = tid & 3;
    int b = (ti * 32) >> 10, hw0 = (ti * 32) & 1023;
    size_t obase = ((size_t)(b * DD + dc * 64 + dy)) * HWH + hw0;
    #pragma unroll
    for (int q = 0; q < 2; ++q) {
        int j = hx * 8 + q * 4;
        float4 w;
        w.x = tile[j + 0][dy];
        w.y = tile[j + 1][dy];
        w.z = tile[j + 2][dy];
        w.w = tile[j + 3][dy];
        *(float4*)&out[obase + j] = w;
    }
}

// ---------------- Launch ---------------------------------------------------
extern "C" void kernel_launch(void* const* d_in, const int* in_sizes, int n_in,
                              void* d_out, int out_size, void* d_ws, size_t ws_size,
                              hipStream_t stream)
{
    const float* x    = (const float*)d_in[0];
    const float* Wg   = (const float*)d_in[1];
    const float* bg   = (const float*)d_in[2];
    const float* Wn   = (const float*)d_in[3];
    const float* bn   = (const float*)d_in[4];
    const float* W1   = (const float*)d_in[5];
    const float* b1   = (const float*)d_in[6];
    const float* W2   = (const float*)d_in[7];
    const float* b2   = (const float*)d_in[8];
    const float* neps = (const float*)d_in[9];

    char* ws = (char*)d_ws;
    int*   cnt   = (int*)(ws + 0);                       // 32 B
    int*   pair0 = (int*)(ws + 512);                     // 8 KB
    int*   pair1 = (int*)(ws + 8704);                    // 8 KB
    int*   ltok  = (int*)(ws + 32768);                   // 64 KB
    float* lgate = (float*)(ws + 98304);                 // 64 KB
    float* part  = (float*)(ws + 163840);                // 1 MB [8][2048][16] f32
    unsigned short* xb   = (unsigned short*)(ws + 1212416);   // 2 MB  [2048][512] bf16
    unsigned short* Hbuf = (unsigned short*)(ws + 3309568);   // 16 MB [4096][2048] bf16
    unsigned short* W1t  = (unsigned short*)(ws + 20086784);  // 16 MB [E][2048][512] bf16
    unsigned short* W2t  = (unsigned short*)(ws + 36864000);  // 16 MB [E][512][2048] bf16
    float*          P4   = (float*)(ws + 53641216);           // 32 MB [4][4096][512] f32

    hipMemsetAsync(cnt, 0, 32, stream);
    moe_prep<<<dim3(256, 8, 4), 256, 0, stream>>>(W1, W2, x, W1t, W2t, xb, Wg, Wn, part);
    moe_router_topk<<<TT / 256, 256, 0, stream>>>(part, bg, bn, neps,
                                                  cnt, pair0, pair1, ltok, lgate);
    moe_gemm1<<<dim3(EE, 32, 16), 256, 0, stream>>>(xb, W1t, b1, cnt, ltok, Hbuf);
    moe_gemm2<<<dim3(EE, 32, 16), 256, 0, stream>>>(Hbuf, W2t, cnt, P4);
    moe_combine<<<dim3(TT / 32, 8), 256, 0, stream>>>(pair0, pair1, cnt, lgate, b2, P4, (float*)d_out);
}

// Round 7
// 91.423 us; speedup vs baseline: 1.2398x; 1.1159x over previous
//
#include <hip/hip_runtime.h>
#include <hip/hip_bf16.h>
#include <math.h>

// Problem constants
#define DD  512
#define EE  8
#define FFD 2048
#define TT  2048
#define HWH 1024

typedef __bf16 b16x8 __attribute__((ext_vector_type(8)));
typedef float  f32x4 __attribute__((ext_vector_type(4)));

__device__ __forceinline__ unsigned short f2bf(float f) {
    unsigned u = __builtin_bit_cast(unsigned, f);
    u = (u + 0x7FFFu + ((u >> 16) & 1u)) >> 16;   // RNE
    return (unsigned short)u;
}

// async global->LDS, 16B per lane; LDS dest is wave-uniform base + lane*16
__device__ __forceinline__ void gload16(const void* g, void* l) {
    __builtin_amdgcn_global_load_lds(
        (const __attribute__((address_space(1))) void*)g,
        (__attribute__((address_space(3))) void*)l, 16, 0, 0);
}

// prefix over cnt without runtime-indexed array (rule #20)
__device__ __forceinline__ int seg_pred(const int* __restrict__ cnt, int e) {
    int s = 0;
    #pragma unroll
    for (int i = 0; i < EE; ++i) s += (i < e) ? cnt[i] : 0;
    return s;
}

// ---------- prep: weight/x transpose-convert + router partial GEMV ---------
// z=0: W1[e] 512x2048 f32 -> W1t[e] 2048x512 bf16   (128 tiles of 128x64)
// z=1: W2[e] 2048x512 f32 -> W2t[e] 512x2048 bf16   (128 tiles)
// z=2: x[b]  512x1024 f32 -> xb[b] 1024x512 bf16    (64 tiles, e<2)
// z=3: router partial GEMV (+ cnt zeroing)
__global__ __launch_bounds__(256) void moe_prep(
    const float* __restrict__ W1, const float* __restrict__ W2,
    const float* __restrict__ x,
    unsigned short* __restrict__ W1t, unsigned short* __restrict__ W2t,
    unsigned short* __restrict__ xb,
    const float* __restrict__ Wg, const float* __restrict__ Wn,
    float* __restrict__ part, int* __restrict__ cnt)
{
    __shared__ float ld[128][65];   // 33.3 KB
    int which = blockIdx.z, e = blockIdx.y;
    int tid = threadIdx.x;

    if (which == 3) {
        if (e == 0 && blockIdx.x == 0 && tid < EE) cnt[tid] = 0;
        if (blockIdx.x >= 32) return;
        int u = tid & 63;
        int q = tid >> 6;
        int tt = blockIdx.x, dc = e;
        int t = tt * 64 + u;
        int b = t >> 10, hw = t & 1023;
        const float* xp = x + (size_t)b * DD * HWH + hw;
        int d0 = dc * 64 + q * 16;
        float accL[EE], accN[EE];
        #pragma unroll
        for (int k = 0; k < EE; ++k) { accL[k] = 0.f; accN[k] = 0.f; }
        #pragma unroll
        for (int i = 0; i < 16; ++i) {
            int d = d0 + i;
            float tv = xp[(size_t)d * HWH];
            #pragma unroll
            for (int k = 0; k < EE; ++k) {
                accL[k] = fmaf(tv, Wg[d * EE + k], accL[k]);
                accN[k] = fmaf(tv, Wn[d * EE + k], accN[k]);
            }
        }
        float (*s)[64][16] = (float (*)[64][16])&ld[0][0];
        #pragma unroll
        for (int k = 0; k < EE; ++k) { s[q][u][k] = accL[k]; s[q][u][k + 8] = accN[k]; }
        __syncthreads();
        int idx = tid * 4;
        int ot = idx >> 4, oc = idx & 15;
        float4 v;
        v.x = s[0][ot][oc+0] + s[1][ot][oc+0] + s[2][ot][oc+0] + s[3][ot][oc+0];
        v.y = s[0][ot][oc+1] + s[1][ot][oc+1] + s[2][ot][oc+1] + s[3][ot][oc+1];
        v.z = s[0][ot][oc+2] + s[1][ot][oc+2] + s[2][ot][oc+2] + s[3][ot][oc+2];
        v.w = s[0][ot][oc+3] + s[1][ot][oc+3] + s[2][ot][oc+3] + s[3][ot][oc+3];
        *(float4*)&part[((size_t)dc * TT + tt * 64 + ot) * 16 + oc] = v;
        return;
    }

    const float* in; unsigned short* out; int R, C;
    if (which == 0)      { R = DD;  C = FFD; in = W1 + (size_t)e*DD*FFD; out = W1t + (size_t)e*FFD*DD; }
    else if (which == 1) { R = FFD; C = DD;  in = W2 + (size_t)e*FFD*DD; out = W2t + (size_t)e*DD*FFD; }
    else { if (e >= 2) return; R = DD; C = HWH; in = x + (size_t)e*DD*HWH; out = xb + (size_t)e*HWH*DD; }
    int tilesC = C >> 6, tilesR = R >> 7;
    if ((int)blockIdx.x >= tilesR * tilesC) return;
    int tr = (blockIdx.x / tilesC) << 7, tc = (blockIdx.x % tilesC) << 6;
    // load 128x64 f32 tile (coalesced 256B row segments)
    int ty = tid >> 4, tx = tid & 15;
    #pragma unroll
    for (int i = 0; i < 8; ++i) {
        int r = ty + i * 16;
        const float4 v = *(const float4*)&in[(size_t)(tr + r)*C + tc + tx*4];
        ld[r][tx*4+0] = v.x; ld[r][tx*4+1] = v.y;
        ld[r][tx*4+2] = v.z; ld[r][tx*4+3] = v.w;
    }
    __syncthreads();
    // store transposed: 16B/lane, 256B contiguous per output row
    int ox = tid & 15;
    #pragma unroll
    for (int it = 0; it < 4; ++it) {
        int c = (tid >> 4) + it * 16;
        uint4 u;
        u.x = f2bf(ld[ox*8+0][c]) | ((unsigned)f2bf(ld[ox*8+1][c]) << 16);
        u.y = f2bf(ld[ox*8+2][c]) | ((unsigned)f2bf(ld[ox*8+3][c]) << 16);
        u.z = f2bf(ld[ox*8+4][c]) | ((unsigned)f2bf(ld[ox*8+5][c]) << 16);
        u.w = f2bf(ld[ox*8+6][c]) | ((unsigned)f2bf(ld[ox*8+7][c]) << 16);
        *(uint4*)&out[(size_t)(tc + c)*R + tr + ox*8] = u;
    }
}

// ---------------- Router stage B: reduce + noisy top-2 + gates -------------
__global__ __launch_bounds__(256) void moe_router_topk(
    const float* __restrict__ part,
    const float* __restrict__ bg, const float* __restrict__ bn,
    const float* __restrict__ neps,
    int* __restrict__ cnt, int* __restrict__ pair0, int* __restrict__ pair1,
    int* __restrict__ ltok, float* __restrict__ lgate)
{
    int t = blockIdx.x * 256 + threadIdx.x;
    float L[EE], N[EE];
    #pragma unroll
    for (int e = 0; e < EE; ++e) { L[e] = bg[e]; N[e] = bn[e]; }
    #pragma unroll
    for (int dc = 0; dc < 8; ++dc) {
        const float* p = &part[((size_t)dc * TT + t) * 16];
        float4 a0 = *(const float4*)&p[0];
        float4 a1 = *(const float4*)&p[4];
        float4 a2 = *(const float4*)&p[8];
        float4 a3 = *(const float4*)&p[12];
        L[0] += a0.x; L[1] += a0.y; L[2] += a0.z; L[3] += a0.w;
        L[4] += a1.x; L[5] += a1.y; L[6] += a1.z; L[7] += a1.w;
        N[0] += a2.x; N[1] += a2.y; N[2] += a2.z; N[3] += a2.w;
        N[4] += a3.x; N[5] += a3.y; N[6] += a3.z; N[7] += a3.w;
    }
    float noisy[EE];
    #pragma unroll
    for (int e = 0; e < EE; ++e) {
        float sp = fmaxf(N[e], 0.f) + log1pf(expf(-fabsf(N[e])));   // softplus
        noisy[e] = L[e] + neps[t * EE + e] * sp;
    }
    int e0 = 0; float v0 = noisy[0];
    #pragma unroll
    for (int e = 1; e < EE; ++e) if (noisy[e] > v0) { v0 = noisy[e]; e0 = e; }
    int e1 = (e0 == 0) ? 1 : 0; float v1 = noisy[e1];
    #pragma unroll
    for (int e = 0; e < EE; ++e)
        if (e != e0 && e != e1 && noisy[e] > v1) { v1 = noisy[e]; e1 = e; }
    float ex  = expf(v1 - v0);
    float inv = 1.f / (1.f + ex);
    float g0 = inv, g1 = ex * inv;
    int p0 = atomicAdd(&cnt[e0], 1);
    int p1 = atomicAdd(&cnt[e1], 1);
    ltok[e0 * TT + p0] = t; lgate[e0 * TT + p0] = g0;
    ltok[e1 * TT + p1] = t; lgate[e1 * TT + p1] = g1;
    pair0[t] = (e0 << 16) | p0;
    pair1[t] = (e1 << 16) | p1;
}

// ---------------- GEMM1: H = relu(tok @ W1t^T + b1) ------------------------
// 64x128 tile, BK=64, dbuf LDS, counted-vmcnt never-drain pipeline (T3/T4).
__global__ __launch_bounds__(256, 3) void moe_gemm1(
    const unsigned short* __restrict__ xb, const unsigned short* __restrict__ W1t,
    const float* __restrict__ b1, const int* __restrict__ cnt,
    const int* __restrict__ ltok, unsigned short* __restrict__ Hbuf)
{
    int e = blockIdx.x, mt = blockIdx.y, nt = blockIdx.z;
    int ce = cnt[e];
    if (mt * 64 >= ce) return;
    int s0 = seg_pred(cnt, e);
    const unsigned short* Be = W1t + (size_t)e * FFD * DD;   // [FF][D] bf16
    __shared__ unsigned short As[2][64 * 64];
    __shared__ unsigned short Bs[2][128 * 64];
    int tid = threadIdx.x, lane = tid & 63, wv = tid >> 6;

    int srow = lane >> 3, schunk = lane & 7;
    int srcoff = ((schunk ^ srow) << 3);       // swizzled source chunk (elems)

    size_t aoff[2]; int ards[2];
    #pragma unroll
    for (int c = 0; c < 2; ++c) {
        int r0 = (c*4 + wv)*8;
        int ri = mt*64 + r0 + srow;
        int tok = ltok[e * TT + (ri < ce ? ri : 0)];
        aoff[c] = (size_t)tok * DD + srcoff;
        ards[c] = r0 * 64;                     // wave-uniform LDS base (elems)
    }
    size_t boff[4]; int brds[4];
    #pragma unroll
    for (int c = 0; c < 4; ++c) {
        int r0 = (c*4 + wv)*8;
        boff[c] = (size_t)(nt*128 + r0 + srow) * DD + srcoff;
        brds[c] = r0 * 64;
    }

    int frow = lane & 15, fk = (lane >> 4) * 8;
    int am = (wv >> 1) * 32, bnn = (wv & 1) * 64;
    int rx = (frow & 7) << 3;

    f32x4 acc[2][4];
    f32x4 zero = {0.f, 0.f, 0.f, 0.f};
    #pragma unroll
    for (int m = 0; m < 2; ++m)
        #pragma unroll
        for (int n = 0; n < 4; ++n) acc[m][n] = zero;

    // prologue: stage tiles 0 and 1 (6 wave-loads each; 12 in flight)
    #pragma unroll
    for (int c = 0; c < 2; ++c) gload16(&xb[aoff[c]], &As[0][ards[c]]);
    #pragma unroll
    for (int c = 0; c < 4; ++c) gload16(&Be[boff[c]], &Bs[0][brds[c]]);
    #pragma unroll
    for (int c = 0; c < 2; ++c) gload16(&xb[aoff[c] + 64], &As[1][ards[c]]);
    #pragma unroll
    for (int c = 0; c < 4; ++c) gload16(&Be[boff[c] + 64], &Bs[1][brds[c]]);

    #pragma unroll
    for (int t = 0; t < 8; ++t) {
        if (t < 6) { asm volatile("s_waitcnt vmcnt(6)" ::: "memory"); }
        else       { asm volatile("s_waitcnt vmcnt(0)" ::: "memory"); }
        __builtin_amdgcn_s_barrier();
        __builtin_amdgcn_sched_barrier(0);
        const int cur = t & 1;
        #pragma unroll
        for (int k2 = 0; k2 < 64; k2 += 32) {
            b16x8 af[2], bf[4];
            #pragma unroll
            for (int m = 0; m < 2; ++m)
                af[m] = *(const b16x8*)&As[cur][(am + m*16 + frow)*64 + ((k2 + fk) ^ rx)];
            #pragma unroll
            for (int n = 0; n < 4; ++n)
                bf[n] = *(const b16x8*)&Bs[cur][(bnn + n*16 + frow)*64 + ((k2 + fk) ^ rx)];
            #pragma unroll
            for (int m = 0; m < 2; ++m)
                #pragma unroll
                for (int n = 0; n < 4; ++n)
                    acc[m][n] = __builtin_amdgcn_mfma_f32_16x16x32_bf16(af[m], bf[n], acc[m][n], 0, 0, 0);
        }
        __builtin_amdgcn_s_barrier();          // all waves done reading buf[cur]
        if (t < 6) {
            int kk = (t + 2) * 64;
            #pragma unroll
            for (int c = 0; c < 2; ++c) gload16(&xb[aoff[c] + kk], &As[cur][ards[c]]);
            #pragma unroll
            for (int c = 0; c < 4; ++c) gload16(&Be[boff[c] + kk], &Bs[cur][brds[c]]);
        }
    }

    int crow = (lane >> 4) * 4;
    #pragma unroll
    for (int m = 0; m < 2; ++m) {
        #pragma unroll
        for (int i = 0; i < 4; ++i) {
            int r = mt*64 + am + m*16 + crow + i;
            if (r < ce) {
                size_t hrow = (size_t)(s0 + r) * FFD;
                #pragma unroll
                for (int n = 0; n < 4; ++n) {
                    int col = nt*128 + bnn + n*16 + frow;
                    float v = acc[m][n][i] + b1[e * FFD + col];
                    Hbuf[hrow + col] = f2bf(fmaxf(v, 0.f));
                }
            }
        }
    }
}

// ---------------- GEMM2: P2[s] = H @ W2t^T  (split-K x2) -------------------
// 64x128 tile, BK=64, counted-vmcnt pipeline; z: split = z>>2, nt = z&3.
__global__ __launch_bounds__(256, 3) void moe_gemm2(
    const unsigned short* __restrict__ Hbuf, const unsigned short* __restrict__ W2t,
    const int* __restrict__ cnt, float* __restrict__ P2)
{
    int e = blockIdx.x, mt = blockIdx.y;
    int split = blockIdx.z >> 2, nt = blockIdx.z & 3;
    int ce = cnt[e];
    if (mt * 64 >= ce) return;
    int s0 = seg_pred(cnt, e);
    int kbase = split * 1024;
    const unsigned short* Be = W2t + (size_t)e * DD * FFD;   // [D][FF] bf16
    __shared__ unsigned short As[2][64 * 64];
    __shared__ unsigned short Bs[2][128 * 64];
    int tid = threadIdx.x, lane = tid & 63, wv = tid >> 6;

    int srow = lane >> 3, schunk = lane & 7;
    int srcoff = ((schunk ^ srow) << 3);

    size_t aoff[2]; int ards[2];
    #pragma unroll
    for (int c = 0; c < 2; ++c) {
        int r0 = (c*4 + wv)*8;
        int g = s0 + mt*64 + r0 + srow; if (g > 4095) g = 4095;
        aoff[c] = (size_t)g * FFD + kbase + srcoff;
        ards[c] = r0 * 64;
    }
    size_t boff[4]; int brds[4];
    #pragma unroll
    for (int c = 0; c < 4; ++c) {
        int r0 = (c*4 + wv)*8;
        boff[c] = (size_t)(nt*128 + r0 + srow) * FFD + kbase + srcoff;
        brds[c] = r0 * 64;
    }

    int frow = lane & 15, fk = (lane >> 4) * 8;
    int am = (wv >> 1) * 32, bnn = (wv & 1) * 64;
    int rx = (frow & 7) << 3;

    f32x4 acc[2][4];
    f32x4 zero = {0.f, 0.f, 0.f, 0.f};
    #pragma unroll
    for (int m = 0; m < 2; ++m)
        #pragma unroll
        for (int n = 0; n < 4; ++n) acc[m][n] = zero;

    #pragma unroll
    for (int c = 0; c < 2; ++c) gload16(&Hbuf[aoff[c]], &As[0][ards[c]]);
    #pragma unroll
    for (int c = 0; c < 4; ++c) gload16(&Be[boff[c]], &Bs[0][brds[c]]);
    #pragma unroll
    for (int c = 0; c < 2; ++c) gload16(&Hbuf[aoff[c] + 64], &As[1][ards[c]]);
    #pragma unroll
    for (int c = 0; c < 4; ++c) gload16(&Be[boff[c] + 64], &Bs[1][brds[c]]);

    #pragma unroll
    for (int t = 0; t < 16; ++t) {
        if (t < 14) { asm volatile("s_waitcnt vmcnt(6)" ::: "memory"); }
        else        { asm volatile("s_waitcnt vmcnt(0)" ::: "memory"); }
        __builtin_amdgcn_s_barrier();
        __builtin_amdgcn_sched_barrier(0);
        const int cur = t & 1;
        #pragma unroll
        for (int k2 = 0; k2 < 64; k2 += 32) {
            b16x8 af[2], bf[4];
            #pragma unroll
            for (int m = 0; m < 2; ++m)
                af[m] = *(const b16x8*)&As[cur][(am + m*16 + frow)*64 + ((k2 + fk) ^ rx)];
            #pragma unroll
            for (int n = 0; n < 4; ++n)
                bf[n] = *(const b16x8*)&Bs[cur][(bnn + n*16 + frow)*64 + ((k2 + fk) ^ rx)];
            #pragma unroll
            for (int m = 0; m < 2; ++m)
                #pragma unroll
                for (int n = 0; n < 4; ++n)
                    acc[m][n] = __builtin_amdgcn_mfma_f32_16x16x32_bf16(af[m], bf[n], acc[m][n], 0, 0, 0);
        }
        __builtin_amdgcn_s_barrier();
        if (t < 14) {
            int kk = (t + 2) * 64;
            #pragma unroll
            for (int c = 0; c < 2; ++c) gload16(&Hbuf[aoff[c] + kk], &As[cur][ards[c]]);
            #pragma unroll
            for (int c = 0; c < 4; ++c) gload16(&Be[boff[c] + kk], &Bs[cur][brds[c]]);
        }
    }

    int crow = (lane >> 4) * 4;
    float* Pw = P2 + (size_t)split * 4096 * DD;
    #pragma unroll
    for (int m = 0; m < 2; ++m) {
        #pragma unroll
        for (int i = 0; i < 4; ++i) {
            int r = mt*64 + am + m*16 + crow + i;
            if (r < ce) {
                size_t prow = (size_t)(s0 + r) * DD;
                #pragma unroll
                for (int n = 0; n < 4; ++n) {
                    int col = nt*128 + bnn + n*16 + frow;
                    Pw[prow + col] = acc[m][n][i];
                }
            }
        }
    }
}

// ------ Combine: out[t,d] = sum_pairs gate*(sum_splits P2 + b2[e])  --------
__global__ __launch_bounds__(256) void moe_combine(
    const int* __restrict__ pair0, const int* __restrict__ pair1,
    const int* __restrict__ cnt, const float* __restrict__ lgate,
    const float* __restrict__ b2, const float* __restrict__ P2,
    float* __restrict__ out)
{
    __shared__ float tile[32][68];
    int tid = threadIdx.x;
    int ti = blockIdx.x, dc = blockIdx.y;
    int ty = tid >> 3, tx = tid & 7;
    int t = ti * 32 + ty;
    int a0 = pair0[t], a1 = pair1[t];
    int e0 = a0 >> 16, sl0 = a0 & 0xFFFF;
    int e1 = a1 >> 16, sl1 = a1 & 0xFFFF;
    int p0 = seg_pred(cnt, e0) + sl0, p1 = seg_pred(cnt, e1) + sl1;
    float g0 = lgate[e0 * TT + sl0], g1 = lgate[e1 * TT + sl1];
    int d0 = dc * 64 + tx * 8;
    f32x4 s0v[2] = {{0,0,0,0},{0,0,0,0}}, s1v[2] = {{0,0,0,0},{0,0,0,0}};
    #pragma unroll
    for (int s = 0; s < 2; ++s) {
        const f32x4* r0p = (const f32x4*)(P2 + ((size_t)s * 4096 + p0) * DD + d0);
        const f32x4* r1p = (const f32x4*)(P2 + ((size_t)s * 4096 + p1) * DD + d0);
        s0v[0] += r0p[0]; s0v[1] += r0p[1];
        s1v[0] += r1p[0]; s1v[1] += r1p[1];
    }
    const f32x4* b0p = (const f32x4*)(b2 + e0 * DD + d0);
    const f32x4* b1p = (const f32x4*)(b2 + e1 * DD + d0);
    #pragma unroll
    for (int q = 0; q < 2; ++q) {
        f32x4 v = g0 * (s0v[q] + b0p[q]) + g1 * (s1v[q] + b1p[q]);
        *(f32x4*)&tile[ty][tx*8 + q*4] = v;
    }
    __syncthreads();
    int dy = tid >> 2, hx = tid & 3;
    int b = (ti * 32) >> 10, hw0 = (ti * 32) & 1023;
    size_t obase = ((size_t)(b * DD + dc * 64 + dy)) * HWH + hw0;
    #pragma unroll
    for (int q = 0; q < 2; ++q) {
        int j = hx * 8 + q * 4;
        float4 w;
        w.x = tile[j + 0][dy];
        w.y = tile[j + 1][dy];
        w.z = tile[j + 2][dy];
        w.w = tile[j + 3][dy];
        *(float4*)&out[obase + j] = w;
    }
}

// ---------------- Launch ---------------------------------------------------
extern "C" void kernel_launch(void* const* d_in, const int* in_sizes, int n_in,
                              void* d_out, int out_size, void* d_ws, size_t ws_size,
                              hipStream_t stream)
{
    const float* x    = (const float*)d_in[0];
    const float* Wg   = (const float*)d_in[1];
    const float* bg   = (const float*)d_in[2];
    const float* Wn   = (const float*)d_in[3];
    const float* bn   = (const float*)d_in[4];
    const float* W1   = (const float*)d_in[5];
    const float* b1   = (const float*)d_in[6];
    const float* W2   = (const float*)d_in[7];
    const float* b2   = (const float*)d_in[8];
    const float* neps = (const float*)d_in[9];

    char* ws = (char*)d_ws;
    int*   cnt   = (int*)(ws + 0);                       // 32 B
    int*   pair0 = (int*)(ws + 512);                     // 8 KB
    int*   pair1 = (int*)(ws + 8704);                    // 8 KB
    int*   ltok  = (int*)(ws + 32768);                   // 64 KB
    float* lgate = (float*)(ws + 98304);                 // 64 KB
    float* part  = (float*)(ws + 163840);                // 1 MB [8][2048][16] f32
    unsigned short* xb   = (unsigned short*)(ws + 1212416);   // 2 MB  [2048][512] bf16
    unsigned short* Hbuf = (unsigned short*)(ws + 3309568);   // 16 MB [4096][2048] bf16
    unsigned short* W1t  = (unsigned short*)(ws + 20086784);  // 16 MB [E][2048][512] bf16
    unsigned short* W2t  = (unsigned short*)(ws + 36864000);  // 16 MB [E][512][2048] bf16
    float*          P2   = (float*)(ws + 53641216);           // 16 MB [2][4096][512] f32

    moe_prep<<<dim3(128, 8, 4), 256, 0, stream>>>(W1, W2, x, W1t, W2t, xb, Wg, Wn, part, cnt);
    moe_router_topk<<<TT / 256, 256, 0, stream>>>(part, bg, bn, neps,
                                                  cnt, pair0, pair1, ltok, lgate);
    moe_gemm1<<<dim3(EE, 32, 16), 256, 0, stream>>>(xb, W1t, b1, cnt, ltok, Hbuf);
    moe_gemm2<<<dim3(EE, 32, 8), 256, 0, stream>>>(Hbuf, W2t, cnt, P2);
    moe_combine<<<dim3(TT / 32, 8), 256, 0, stream>>>(pair0, pair1, cnt, lgate, b2, P2, (float*)d_out);
}